// Round 1
// baseline (1663.757 us; speedup 1.0000x reference)
//
#include <hip/hip_runtime.h>
#include <math.h>

// ---------------- MLP: x[N,1] -> 16 -> 32 -> 64, ReLU each ----------------
__global__ void mlp_kernel(const float* __restrict__ x,
                           const float* __restrict__ w1, const float* __restrict__ b1,
                           const float* __restrict__ w2, const float* __restrict__ b2,
                           const float* __restrict__ w3, const float* __restrict__ b3,
                           float* __restrict__ h0, int n) {
    __shared__ float sw1[16], sb1[16], sw2[32 * 16], sb2[32], sw3[64 * 32], sb3[64];
    int tid = threadIdx.x;
    if (tid < 16) { sw1[tid] = w1[tid]; sb1[tid] = b1[tid]; }
    if (tid < 32) sb2[tid] = b2[tid];
    if (tid < 64) sb3[tid] = b3[tid];
    for (int i = tid; i < 512; i += 256) sw2[i] = w2[i];
    for (int i = tid; i < 2048; i += 256) sw3[i] = w3[i];
    __syncthreads();
    int node = blockIdx.x * 256 + tid;
    if (node >= n) return;
    float xv = x[node];
    float t1[16], t2[32];
#pragma unroll
    for (int i = 0; i < 16; i++) t1[i] = fmaxf(sw1[i] * xv + sb1[i], 0.f);
#pragma unroll
    for (int o = 0; o < 32; o++) {
        float a = sb2[o];
#pragma unroll
        for (int i = 0; i < 16; i++) a += sw2[o * 16 + i] * t1[i];
        t2[o] = fmaxf(a, 0.f);
    }
    float* hr = h0 + (size_t)node * 64;
    for (int o = 0; o < 64; o++) {
        float a = sb3[o];
#pragma unroll
        for (int i = 0; i < 32; i++) a += sw3[o * 32 + i] * t2[i];
        hr[o] = fmaxf(a, 0.f);
    }
}

// ---------------- fp32 tiled GEMM: C[n][o] = sum_k A[n][k] * W[o][k] ----------------
// A:[N,K] row-major, W:[O,K] row-major (both contiguous along K -> coalesced loads)
__global__ void gemm_nt(const float* __restrict__ A, const float* __restrict__ W,
                        float* __restrict__ C, int n, int K, int O) {
    __shared__ float As[64][17];  // +1 pad breaks bank conflicts
    __shared__ float Bs[64][17];
    int tid = threadIdx.x;
    int row0 = blockIdx.x * 64, col0 = blockIdx.y * 64;
    int rm = tid >> 4, cn = tid & 15;
    float acc[4][4] = {};
    for (int k0 = 0; k0 < K; k0 += 16) {
#pragma unroll
        for (int i = tid; i < 1024; i += 256) {
            int m = i >> 4, k = i & 15;
            int gr = row0 + m;
            As[m][k] = (gr < n) ? A[(size_t)gr * K + k0 + k] : 0.f;
        }
#pragma unroll
        for (int i = tid; i < 1024; i += 256) {
            int m = i >> 4, k = i & 15;
            int go = col0 + m;
            Bs[m][k] = (go < O) ? W[(size_t)go * K + k0 + k] : 0.f;
        }
        __syncthreads();
#pragma unroll
        for (int k = 0; k < 16; k++) {
            float a[4], b[4];
#pragma unroll
            for (int i = 0; i < 4; i++) a[i] = As[rm * 4 + i][k];
#pragma unroll
            for (int j = 0; j < 4; j++) b[j] = Bs[cn * 4 + j][k];
#pragma unroll
            for (int i = 0; i < 4; i++)
#pragma unroll
                for (int j = 0; j < 4; j++) acc[i][j] += a[i] * b[j];
        }
        __syncthreads();
    }
#pragma unroll
    for (int i = 0; i < 4; i++) {
        int gr = row0 + rm * 4 + i;
        if (gr >= n) continue;
#pragma unroll
        for (int j = 0; j < 4; j++) {
            int go = col0 + cn * 4 + j;
            if (go < O) C[(size_t)gr * O + go] = acc[i][j];
        }
    }
}

// ---------------- per-node attention logits: as[v]=h[v].a_s, ad[v]=h[v].a_d ----------------
__global__ void alpha_kernel(const float* __restrict__ hl, const float* __restrict__ avs,
                             const float* __restrict__ avd, float* __restrict__ as_,
                             float* __restrict__ ad_, int n, int O) {
    int gt = blockIdx.x * blockDim.x + threadIdx.x;
    int v = gt >> 6, lane = gt & 63;
    if (v >= n) return;
    const float* hr = hl + (size_t)v * O;
    float s1 = 0.f, s2 = 0.f;
    for (int f = lane; f < O; f += 64) {
        float h = hr[f];
        s1 += h * avs[f];
        s2 += h * avd[f];
    }
    for (int o = 32; o > 0; o >>= 1) {
        s1 += __shfl_xor(s1, o);
        s2 += __shfl_xor(s2, o);
    }
    if (lane == 0) { as_[v] = s1; ad_[v] = s2; }
}

// ---------------- CSR build (by dst), self-loops appended at e >= E ----------------
__global__ void hist_kernel(const int* __restrict__ dst, int* __restrict__ deg, int E, int n) {
    int e = blockIdx.x * 256 + threadIdx.x;
    if (e >= E + n) return;
    int d = (e < E) ? dst[e] : (e - E);
    atomicAdd(&deg[d], 1);
}

__global__ void scan_block_sums(const int* __restrict__ deg, int* __restrict__ bsums, int n) {
    __shared__ int sdata[256];
    int tid = threadIdx.x;
    int base = blockIdx.x * 1024 + tid * 4;
    int s = 0;
    for (int i = 0; i < 4; i++) {
        int g = base + i;
        if (g < n) s += deg[g];
    }
    sdata[tid] = s;
    __syncthreads();
    for (int off = 128; off > 0; off >>= 1) {
        if (tid < off) sdata[tid] += sdata[tid + off];
        __syncthreads();
    }
    if (tid == 0) bsums[blockIdx.x] = sdata[0];
}

__global__ void scan_bsums(int* bsums, int nb, int* rowptr, int n) {
    if (threadIdx.x == 0 && blockIdx.x == 0) {
        int acc = 0;
        for (int i = 0; i < nb; i++) {
            int t = bsums[i];
            bsums[i] = acc;
            acc += t;
        }
        rowptr[n] = acc;  // total = E + n
    }
}

__global__ void scan_write(const int* __restrict__ deg, const int* __restrict__ bsums,
                           int* __restrict__ rowptr, int* __restrict__ cursor, int n) {
    __shared__ int sdata[256];
    int tid = threadIdx.x;
    int base = blockIdx.x * 1024 + tid * 4;
    int v[4];
    int s = 0;
    for (int i = 0; i < 4; i++) {
        int g = base + i;
        v[i] = (g < n) ? deg[g] : 0;
        s += v[i];
    }
    sdata[tid] = s;
    __syncthreads();
    for (int off = 1; off < 256; off <<= 1) {  // inclusive Hillis-Steele
        int t = (tid >= off) ? sdata[tid - off] : 0;
        __syncthreads();
        sdata[tid] += t;
        __syncthreads();
    }
    int excl = sdata[tid] - s + bsums[blockIdx.x];
    for (int i = 0; i < 4; i++) {
        int g = base + i;
        if (g < n) { rowptr[g] = excl; cursor[g] = excl; }
        excl += v[i];
    }
}

__global__ void scatter_kernel(const int* __restrict__ esrc_in, const int* __restrict__ edst_in,
                               int* __restrict__ cursor, int* __restrict__ esrc, int E, int n) {
    int e = blockIdx.x * 256 + threadIdx.x;
    if (e >= E + n) return;
    int s, d;
    if (e < E) { s = esrc_in[e]; d = edst_in[e]; }
    else { s = e - E; d = e - E; }
    int pos = atomicAdd(&cursor[d], 1);
    esrc[pos] = s;
}

// ---------------- GAT aggregation: one wave per dst node, exact segment softmax ----------------
__global__ void gat_aggregate(const float* __restrict__ hl, const float* __restrict__ as_,
                              const float* __restrict__ ad_, const int* __restrict__ rowptr,
                              const int* __restrict__ esrc, const float* __restrict__ bias,
                              float* __restrict__ hout, int n, int O) {
    int gt = blockIdx.x * blockDim.x + threadIdx.x;
    int v = gt >> 6, lane = gt & 63;
    if (v >= n) return;
    int beg = rowptr[v], end = rowptr[v + 1];
    float adv = ad_[v];
    // pass 1: segment max (every node has a self-loop, so deg >= 1)
    float mymax = -1e30f;
    for (int j = beg + lane; j < end; j += 64) {
        float e = as_[esrc[j]] + adv;
        e = (e > 0.f) ? e : 0.2f * e;
        mymax = fmaxf(mymax, e);
    }
    for (int o = 32; o > 0; o >>= 1) mymax = fmaxf(mymax, __shfl_xor(mymax, o));
    // pass 2: denominator
    float mysum = 0.f;
    for (int j = beg + lane; j < end; j += 64) {
        float e = as_[esrc[j]] + adv;
        e = (e > 0.f) ? e : 0.2f * e;
        mysum += __expf(e - mymax);
    }
    for (int o = 32; o > 0; o >>= 1) mysum += __shfl_xor(mysum, o);
    float invden = 1.f / mysum;
    // pass 3: weighted feature aggregation, lanes parallel over features
    float acc[4] = {0.f, 0.f, 0.f, 0.f};
    for (int j = beg; j < end; ++j) {
        int s = esrc[j];
        float e = as_[s] + adv;
        e = (e > 0.f) ? e : 0.2f * e;
        float alpha = __expf(e - mymax) * invden;
        const float* hr = hl + (size_t)s * O;
#pragma unroll
        for (int k = 0; k < 4; k++) {
            int f = lane + (k << 6);
            if (f < O) acc[k] += alpha * hr[f];
        }
    }
    float* outr = hout + (size_t)v * O;
#pragma unroll
    for (int k = 0; k < 4; k++) {
        int f = lane + (k << 6);
        if (f < O) outr[f] = fmaxf(acc[k] + bias[f], 0.f);
    }
}

// ---------------- pooling + readout ----------------
__global__ void pool_kernel(const float* __restrict__ h, const int* __restrict__ batch,
                            float* __restrict__ sums, float* __restrict__ cnt, int n) {
    int gt = blockIdx.x * blockDim.x + threadIdx.x;
    int node = gt >> 5, f = gt & 31;
    if (node >= n) return;
    int g = batch[node];
    atomicAdd(&sums[g * 32 + f], h[(size_t)node * 32 + f]);
    if (f == 0) atomicAdd(&cnt[g], 1.f);
}

__global__ void final_kernel(const float* __restrict__ sums, const float* __restrict__ cnt,
                             const float* __restrict__ lw, const float* __restrict__ lb,
                             float* __restrict__ out, int G) {
    int g = blockIdx.x * blockDim.x + threadIdx.x;
    if (g >= G) return;
    float inv = 1.f / fmaxf(cnt[g], 1.f);
    float a = lb[0];
    for (int f = 0; f < 32; f++) a += sums[g * 32 + f] * inv * lw[f];
    out[g] = 1.f / (1.f + __expf(-a));
}

extern "C" void kernel_launch(void* const* d_in, const int* in_sizes, int n_in,
                              void* d_out, int out_size, void* d_ws, size_t ws_size,
                              hipStream_t stream) {
    const float* x = (const float*)d_in[0];
    const int* ei = (const int*)d_in[1];
    const int* batch = (const int*)d_in[2];
    const float* w1 = (const float*)d_in[3];
    const float* b1 = (const float*)d_in[4];
    const float* w2 = (const float*)d_in[5];
    const float* b2 = (const float*)d_in[6];
    const float* w3 = (const float*)d_in[7];
    const float* b3 = (const float*)d_in[8];
    const float* gw[5];
    const float* gas[5];
    const float* gad[5];
    const float* gb[5];
    for (int l = 0; l < 5; l++) {
        gw[l] = (const float*)d_in[9 + l * 4 + 0];
        gas[l] = (const float*)d_in[9 + l * 4 + 1];
        gad[l] = (const float*)d_in[9 + l * 4 + 2];
        gb[l] = (const float*)d_in[9 + l * 4 + 3];
    }
    const float* lw = (const float*)d_in[29];
    const float* lb = (const float*)d_in[30];
    float* out = (float*)d_out;

    int N = in_sizes[0];      // x is [N,1]
    int E = in_sizes[1] / 2;  // edge_index [2,E]
    int G = out_size;         // output [G,1]
    int Etot = E + N;

    char* ws = (char*)d_ws;
    size_t off = 0;
    auto alloc = [&](size_t bytes) -> void* {
        void* p = ws + off;
        off = (off + bytes + 255) & ~(size_t)255;
        return p;
    };
    float* bufA = (float*)alloc((size_t)N * 256 * 4);  // h in / aggregated out (ping)
    float* bufB = (float*)alloc((size_t)N * 256 * 4);  // linear projection hl (pong)
    float* asb = (float*)alloc((size_t)N * 4);
    float* adb = (float*)alloc((size_t)N * 4);
    int* deg = (int*)alloc((size_t)N * 4);
    int* rowptr = (int*)alloc((size_t)(N + 1) * 4);
    int* cursor = (int*)alloc((size_t)(N + 1) * 4);
    int* esrc = (int*)alloc((size_t)Etot * 4);
    int* bsums = (int*)alloc(4096);
    float* sums = (float*)alloc((size_t)G * 32 * 4);
    float* cnt = (float*)alloc((size_t)G * 4);
    (void)ws_size;
    (void)n_in;

    // 1. node MLP -> bufA [N,64]
    mlp_kernel<<<(N + 255) / 256, 256, 0, stream>>>(x, w1, b1, w2, b2, w3, b3, bufA, N);

    // 2. CSR by dst (edges + self-loops)
    hipMemsetAsync(deg, 0, (size_t)N * 4, stream);
    hist_kernel<<<(Etot + 255) / 256, 256, 0, stream>>>(ei + E, deg, E, N);
    int nb = (N + 1023) / 1024;
    scan_block_sums<<<nb, 256, 0, stream>>>(deg, bsums, N);
    scan_bsums<<<1, 64, 0, stream>>>(bsums, nb, rowptr, N);
    scan_write<<<nb, 256, 0, stream>>>(deg, bsums, rowptr, cursor, N);
    scatter_kernel<<<(Etot + 255) / 256, 256, 0, stream>>>(ei, ei + E, cursor, esrc, E, N);

    // 3. five GAT layers
    const int Ks[5] = {64, 128, 256, 128, 64};
    const int Os[5] = {128, 256, 128, 64, 32};
    for (int l = 0; l < 5; l++) {
        int K = Ks[l], O = Os[l];
        dim3 grid((N + 63) / 64, (O + 63) / 64);
        gemm_nt<<<grid, 256, 0, stream>>>(bufA, gw[l], bufB, N, K, O);
        int nwthreads = N * 64;
        alpha_kernel<<<(nwthreads + 255) / 256, 256, 0, stream>>>(bufB, gas[l], gad[l], asb, adb, N, O);
        gat_aggregate<<<(nwthreads + 255) / 256, 256, 0, stream>>>(bufB, asb, adb, rowptr, esrc,
                                                                   gb[l], bufA, N, O);
    }

    // 4. mean pool + linear + sigmoid
    hipMemsetAsync(sums, 0, (size_t)G * 32 * 4, stream);
    hipMemsetAsync(cnt, 0, (size_t)G * 4, stream);
    pool_kernel<<<(N * 32 + 255) / 256, 256, 0, stream>>>(bufA, batch, sums, cnt, N);
    final_kernel<<<(G + 255) / 256, 256, 0, stream>>>(sums, cnt, lw, lb, out, G);
}

// Round 2
// 993.460 us; speedup vs baseline: 1.6747x; 1.6747x over previous
//
#include <hip/hip_runtime.h>
#include <math.h>

// ---------------- MLP: x[N,1] -> 16 -> 32 -> 64, ReLU each ----------------
__global__ void mlp_kernel(const float* __restrict__ x,
                           const float* __restrict__ w1, const float* __restrict__ b1,
                           const float* __restrict__ w2, const float* __restrict__ b2,
                           const float* __restrict__ w3, const float* __restrict__ b3,
                           float* __restrict__ h0, int n) {
    __shared__ float sw1[16], sb1[16], sw2[32 * 16], sb2[32], sw3[64 * 32], sb3[64];
    int tid = threadIdx.x;
    if (tid < 16) { sw1[tid] = w1[tid]; sb1[tid] = b1[tid]; }
    if (tid < 32) sb2[tid] = b2[tid];
    if (tid < 64) sb3[tid] = b3[tid];
    for (int i = tid; i < 512; i += 256) sw2[i] = w2[i];
    for (int i = tid; i < 2048; i += 256) sw3[i] = w3[i];
    __syncthreads();
    int node = blockIdx.x * 256 + tid;
    if (node >= n) return;
    float xv = x[node];
    float t1[16], t2[32];
#pragma unroll
    for (int i = 0; i < 16; i++) t1[i] = fmaxf(sw1[i] * xv + sb1[i], 0.f);
#pragma unroll
    for (int o = 0; o < 32; o++) {
        float a = sb2[o];
#pragma unroll
        for (int i = 0; i < 16; i++) a += sw2[o * 16 + i] * t1[i];
        t2[o] = fmaxf(a, 0.f);
    }
    float* hr = h0 + (size_t)node * 64;
    for (int o = 0; o < 64; o++) {
        float a = sb3[o];
#pragma unroll
        for (int i = 0; i < 32; i++) a += sw3[o * 32 + i] * t2[i];
        hr[o] = fmaxf(a, 0.f);
    }
}

// ---------------- fp32 GEMM 128x64 tile, 8x4 microtile, fused alpha epilogue ----------------
// C[r][o] = sum_k A[r][k]*W[o][k];  as_[r] += sum_o C[r][o]*avs[o] (atomic), same ad_.
// A:[n,K], W:[O,K] row-major, K multiple of 16, O multiple of 32.
__global__ __launch_bounds__(256) void gemm_nt(
    const float* __restrict__ A, const float* __restrict__ W, float* __restrict__ C,
    const float* __restrict__ avs, const float* __restrict__ avd,
    float* __restrict__ as_, float* __restrict__ ad_, int n, int K, int O) {
    __shared__ float As[16][132];  // [k][m], pad+4: write banks 2-way max (free)
    __shared__ float Bs[16][68];   // [k][o]
    int tid = threadIdx.x;
    int row0 = blockIdx.x * 128, col0 = blockIdx.y * 64;
    int tx = tid & 15, ty = tid >> 4;  // ty: 8-row group, tx: 4-col group
    float acc[8][4] = {};
    for (int k0 = 0; k0 < K; k0 += 16) {
        // A tile: 128x16 = 512 float4, 2 per thread
#pragma unroll
        for (int t = 0; t < 2; t++) {
            int i = tid + t * 256;
            int m = i >> 2, k4 = i & 3;
            int gr = row0 + m;
            float4 a = make_float4(0.f, 0.f, 0.f, 0.f);
            if (gr < n) a = *(const float4*)&A[(size_t)gr * K + k0 + k4 * 4];
            As[k4 * 4 + 0][m] = a.x;
            As[k4 * 4 + 1][m] = a.y;
            As[k4 * 4 + 2][m] = a.z;
            As[k4 * 4 + 3][m] = a.w;
        }
        // B tile: 64x16 = 256 float4, 1 per thread
        {
            int m = tid >> 2, k4 = tid & 3;
            int go = col0 + m;
            float4 b = make_float4(0.f, 0.f, 0.f, 0.f);
            if (go < O) b = *(const float4*)&W[(size_t)go * K + k0 + k4 * 4];
            Bs[k4 * 4 + 0][m] = b.x;
            Bs[k4 * 4 + 1][m] = b.y;
            Bs[k4 * 4 + 2][m] = b.z;
            Bs[k4 * 4 + 3][m] = b.w;
        }
        __syncthreads();
#pragma unroll
        for (int k = 0; k < 16; k++) {
            float4 a0 = *(const float4*)&As[k][ty * 8];
            float4 a1 = *(const float4*)&As[k][ty * 8 + 4];
            float4 b0 = *(const float4*)&Bs[k][tx * 4];
            float av[8] = {a0.x, a0.y, a0.z, a0.w, a1.x, a1.y, a1.z, a1.w};
            float bv[4] = {b0.x, b0.y, b0.z, b0.w};
#pragma unroll
            for (int i = 0; i < 8; i++)
#pragma unroll
                for (int j = 0; j < 4; j++) acc[i][j] += av[i] * bv[j];
        }
        __syncthreads();
    }
    // alpha vectors for this 4-col slice
    int gc = col0 + tx * 4;
    float4 vs = make_float4(0.f, 0.f, 0.f, 0.f), vd = vs;
    if (gc < O) { vs = *(const float4*)&avs[gc]; vd = *(const float4*)&avd[gc]; }
#pragma unroll
    for (int i = 0; i < 8; i++) {
        int gr = row0 + ty * 8 + i;
        bool rok = gr < n;
        if (rok && gc < O) *(float4*)&C[(size_t)gr * O + gc] =
            make_float4(acc[i][0], acc[i][1], acc[i][2], acc[i][3]);
        // fused alpha: partial dot over this thread's 4 cols, reduce over 16 tx lanes
        float ps = acc[i][0] * vs.x + acc[i][1] * vs.y + acc[i][2] * vs.z + acc[i][3] * vs.w;
        float pd = acc[i][0] * vd.x + acc[i][1] * vd.y + acc[i][2] * vd.z + acc[i][3] * vd.w;
#pragma unroll
        for (int o = 8; o > 0; o >>= 1) {
            ps += __shfl_xor(ps, o);
            pd += __shfl_xor(pd, o);
        }
        if (tx == 0 && rok) {
            atomicAdd(&as_[gr], ps);
            atomicAdd(&ad_[gr], pd);
        }
    }
}

// ---------------- CSR build (by dst), self-loops appended at e >= E ----------------
__global__ void hist_kernel(const int* __restrict__ dst, int* __restrict__ deg, int E, int n) {
    int e = blockIdx.x * 256 + threadIdx.x;
    if (e >= E + n) return;
    int d = (e < E) ? dst[e] : (e - E);
    atomicAdd(&deg[d], 1);
}

__global__ void scan_block_sums(const int* __restrict__ deg, int* __restrict__ bsums, int n) {
    __shared__ int sdata[256];
    int tid = threadIdx.x;
    int base = blockIdx.x * 1024 + tid * 4;
    int s = 0;
    for (int i = 0; i < 4; i++) {
        int g = base + i;
        if (g < n) s += deg[g];
    }
    sdata[tid] = s;
    __syncthreads();
    for (int off = 128; off > 0; off >>= 1) {
        if (tid < off) sdata[tid] += sdata[tid + off];
        __syncthreads();
    }
    if (tid == 0) bsums[blockIdx.x] = sdata[0];
}

__global__ void scan_bsums(int* bsums, int nb, int* rowptr, int n) {
    if (threadIdx.x == 0 && blockIdx.x == 0) {
        int acc = 0;
        for (int i = 0; i < nb; i++) {
            int t = bsums[i];
            bsums[i] = acc;
            acc += t;
        }
        rowptr[n] = acc;
    }
}

__global__ void scan_write(const int* __restrict__ deg, const int* __restrict__ bsums,
                           int* __restrict__ rowptr, int* __restrict__ cursor, int n) {
    __shared__ int sdata[256];
    int tid = threadIdx.x;
    int base = blockIdx.x * 1024 + tid * 4;
    int v[4];
    int s = 0;
    for (int i = 0; i < 4; i++) {
        int g = base + i;
        v[i] = (g < n) ? deg[g] : 0;
        s += v[i];
    }
    sdata[tid] = s;
    __syncthreads();
    for (int off = 1; off < 256; off <<= 1) {
        int t = (tid >= off) ? sdata[tid - off] : 0;
        __syncthreads();
        sdata[tid] += t;
        __syncthreads();
    }
    int excl = sdata[tid] - s + bsums[blockIdx.x];
    for (int i = 0; i < 4; i++) {
        int g = base + i;
        if (g < n) { rowptr[g] = excl; cursor[g] = excl; }
        excl += v[i];
    }
}

__global__ void scatter_kernel(const int* __restrict__ esrc_in, const int* __restrict__ edst_in,
                               int* __restrict__ cursor, int* __restrict__ esrc, int E, int n) {
    int e = blockIdx.x * 256 + threadIdx.x;
    if (e >= E + n) return;
    int s, d;
    if (e < E) { s = esrc_in[e]; d = edst_in[e]; }
    else { s = e - E; d = e - E; }
    int pos = atomicAdd(&cursor[d], 1);
    esrc[pos] = s;
}

// ---------------- GAT aggregation: one wave per dst node ----------------
// pass 3 vectorized: float4 gathers, 64/(O/4) edges processed per wave iteration.
template <int O>
__global__ void gat_aggregate(const float* __restrict__ hl, const float* __restrict__ as_,
                              const float* __restrict__ ad_, const int* __restrict__ rowptr,
                              const int* __restrict__ esrc, const float* __restrict__ bias,
                              float* __restrict__ hout, int n) {
    constexpr int C4 = O / 4;        // float4 chunks per feature row
    constexpr int EPW = 64 / C4;     // edges per wave iteration
    int v = blockIdx.x * 4 + (threadIdx.x >> 6);
    int lane = threadIdx.x & 63;
    if (v >= n) return;
    int beg = rowptr[v], end = rowptr[v + 1];
    float adv = ad_[v];
    // pass 1: segment max (deg >= 1 due to self-loop)
    float mymax = -1e30f;
    for (int j = beg + lane; j < end; j += 64) {
        float e = as_[esrc[j]] + adv;
        e = (e > 0.f) ? e : 0.2f * e;
        mymax = fmaxf(mymax, e);
    }
#pragma unroll
    for (int o = 32; o > 0; o >>= 1) mymax = fmaxf(mymax, __shfl_xor(mymax, o));
    // pass 2: denominator
    float mysum = 0.f;
    for (int j = beg + lane; j < end; j += 64) {
        float e = as_[esrc[j]] + adv;
        e = (e > 0.f) ? e : 0.2f * e;
        mysum += __expf(e - mymax);
    }
#pragma unroll
    for (int o = 32; o > 0; o >>= 1) mysum += __shfl_xor(mysum, o);
    float invden = 1.f / mysum;
    // pass 3: weighted aggregation, EPW edges concurrent, float4 per lane
    int sub = lane / C4;
    int c = lane % C4;
    float4 acc = make_float4(0.f, 0.f, 0.f, 0.f);
    for (int j0 = beg; j0 < end; j0 += EPW) {
        int j = j0 + sub;
        bool valid = j < end;
        int s = valid ? esrc[j] : v;
        float e = as_[s] + adv;
        e = (e > 0.f) ? e : 0.2f * e;
        float alpha = valid ? __expf(e - mymax) * invden : 0.f;
        float4 hv = ((const float4*)(hl + (size_t)s * O))[c];
        acc.x += alpha * hv.x;
        acc.y += alpha * hv.y;
        acc.z += alpha * hv.z;
        acc.w += alpha * hv.w;
    }
#pragma unroll
    for (int o = C4; o < 64; o <<= 1) {
        acc.x += __shfl_xor(acc.x, o);
        acc.y += __shfl_xor(acc.y, o);
        acc.z += __shfl_xor(acc.z, o);
        acc.w += __shfl_xor(acc.w, o);
    }
    if (sub == 0) {
        float4 bv = ((const float4*)bias)[c];
        float4 r = make_float4(fmaxf(acc.x + bv.x, 0.f), fmaxf(acc.y + bv.y, 0.f),
                               fmaxf(acc.z + bv.z, 0.f), fmaxf(acc.w + bv.w, 0.f));
        ((float4*)(hout + (size_t)v * O))[c] = r;
    }
}

// ---------------- pooling + readout ----------------
__global__ void pool_kernel(const float* __restrict__ h, const int* __restrict__ batch,
                            float* __restrict__ sums, float* __restrict__ cnt, int n) {
    int gt = blockIdx.x * blockDim.x + threadIdx.x;
    int node = gt >> 5, f = gt & 31;
    if (node >= n) return;
    int g = batch[node];
    atomicAdd(&sums[g * 32 + f], h[(size_t)node * 32 + f]);
    if (f == 0) atomicAdd(&cnt[g], 1.f);
}

__global__ void final_kernel(const float* __restrict__ sums, const float* __restrict__ cnt,
                             const float* __restrict__ lw, const float* __restrict__ lb,
                             float* __restrict__ out, int G) {
    int g = blockIdx.x * blockDim.x + threadIdx.x;
    if (g >= G) return;
    float inv = 1.f / fmaxf(cnt[g], 1.f);
    float a = lb[0];
    for (int f = 0; f < 32; f++) a += sums[g * 32 + f] * inv * lw[f];
    out[g] = 1.f / (1.f + __expf(-a));
}

extern "C" void kernel_launch(void* const* d_in, const int* in_sizes, int n_in,
                              void* d_out, int out_size, void* d_ws, size_t ws_size,
                              hipStream_t stream) {
    const float* x = (const float*)d_in[0];
    const int* ei = (const int*)d_in[1];
    const int* batch = (const int*)d_in[2];
    const float* w1 = (const float*)d_in[3];
    const float* b1 = (const float*)d_in[4];
    const float* w2 = (const float*)d_in[5];
    const float* b2 = (const float*)d_in[6];
    const float* w3 = (const float*)d_in[7];
    const float* b3 = (const float*)d_in[8];
    const float* gw[5];
    const float* gas[5];
    const float* gad[5];
    const float* gb[5];
    for (int l = 0; l < 5; l++) {
        gw[l] = (const float*)d_in[9 + l * 4 + 0];
        gas[l] = (const float*)d_in[9 + l * 4 + 1];
        gad[l] = (const float*)d_in[9 + l * 4 + 2];
        gb[l] = (const float*)d_in[9 + l * 4 + 3];
    }
    const float* lw = (const float*)d_in[29];
    const float* lb = (const float*)d_in[30];
    float* out = (float*)d_out;

    int N = in_sizes[0];
    int E = in_sizes[1] / 2;
    int G = out_size;
    int Etot = E + N;

    char* ws = (char*)d_ws;
    size_t off = 0;
    auto alloc = [&](size_t bytes) -> void* {
        void* p = ws + off;
        off = (off + bytes + 255) & ~(size_t)255;
        return p;
    };
    float* bufA = (float*)alloc((size_t)N * 256 * 4);
    float* bufB = (float*)alloc((size_t)N * 256 * 4);
    float* asb = (float*)alloc((size_t)N * 4);
    float* adb = (float*)alloc((size_t)N * 4);
    int* deg = (int*)alloc((size_t)N * 4);
    int* rowptr = (int*)alloc((size_t)(N + 1) * 4);
    int* cursor = (int*)alloc((size_t)(N + 1) * 4);
    int* esrc = (int*)alloc((size_t)Etot * 4);
    int* bsums = (int*)alloc(4096);
    float* sums = (float*)alloc((size_t)G * 32 * 4);
    float* cnt = (float*)alloc((size_t)G * 4);
    (void)ws_size;
    (void)n_in;

    // 1. node MLP -> bufA [N,64]
    mlp_kernel<<<(N + 255) / 256, 256, 0, stream>>>(x, w1, b1, w2, b2, w3, b3, bufA, N);

    // 2. CSR by dst (edges + self-loops)
    hipMemsetAsync(deg, 0, (size_t)N * 4, stream);
    hist_kernel<<<(Etot + 255) / 256, 256, 0, stream>>>(ei + E, deg, E, N);
    int nb = (N + 1023) / 1024;
    scan_block_sums<<<nb, 256, 0, stream>>>(deg, bsums, N);
    scan_bsums<<<1, 64, 0, stream>>>(bsums, nb, rowptr, N);
    scan_write<<<nb, 256, 0, stream>>>(deg, bsums, rowptr, cursor, N);
    scatter_kernel<<<(Etot + 255) / 256, 256, 0, stream>>>(ei, ei + E, cursor, esrc, E, N);

    // 3. five GAT layers (GEMM w/ fused alpha, then softmax-aggregate)
    const int Ks[5] = {64, 128, 256, 128, 64};
    const int Os[5] = {128, 256, 128, 64, 32};
    int aggBlocks = (N + 3) / 4;
    for (int l = 0; l < 5; l++) {
        int K = Ks[l], O = Os[l];
        hipMemsetAsync(asb, 0, (size_t)N * 4, stream);
        hipMemsetAsync(adb, 0, (size_t)N * 4, stream);
        dim3 grid((N + 127) / 128, (O + 63) / 64);
        gemm_nt<<<grid, 256, 0, stream>>>(bufA, gw[l], bufB, gas[l], gad[l], asb, adb, N, K, O);
        switch (O) {
            case 256:
                gat_aggregate<256><<<aggBlocks, 256, 0, stream>>>(bufB, asb, adb, rowptr, esrc,
                                                                  gb[l], bufA, N);
                break;
            case 128:
                gat_aggregate<128><<<aggBlocks, 256, 0, stream>>>(bufB, asb, adb, rowptr, esrc,
                                                                  gb[l], bufA, N);
                break;
            case 64:
                gat_aggregate<64><<<aggBlocks, 256, 0, stream>>>(bufB, asb, adb, rowptr, esrc,
                                                                 gb[l], bufA, N);
                break;
            default:
                gat_aggregate<32><<<aggBlocks, 256, 0, stream>>>(bufB, asb, adb, rowptr, esrc,
                                                                 gb[l], bufA, N);
                break;
        }
    }

    // 4. mean pool + linear + sigmoid
    hipMemsetAsync(sums, 0, (size_t)G * 32 * 4, stream);
    hipMemsetAsync(cnt, 0, (size_t)G * 4, stream);
    pool_kernel<<<(N * 32 + 255) / 256, 256, 0, stream>>>(bufA, batch, sums, cnt, N);
    final_kernel<<<(G + 255) / 256, 256, 0, stream>>>(sums, cnt, lw, lb, out, G);
}

// Round 3
// 800.488 us; speedup vs baseline: 2.0784x; 1.2411x over previous
//
#include <hip/hip_runtime.h>
#include <math.h>

typedef __attribute__((ext_vector_type(8))) __bf16 bf16x8;
typedef __attribute__((ext_vector_type(4))) float f32x4;

__device__ inline unsigned short f2bf(float f) {  // RNE
    unsigned int i = __float_as_uint(f);
    unsigned int r = i + 0x7fffu + ((i >> 16) & 1u);
    return (unsigned short)(r >> 16);
}
__device__ inline float bf2f(unsigned short u) {
    return __uint_as_float(((unsigned int)u) << 16);
}

// ---------------- fp32 -> bf16 weight conversion ----------------
__global__ void f2bf_kernel(const float* __restrict__ src, unsigned short* __restrict__ dst,
                            int cnt) {
    int i = blockIdx.x * 256 + threadIdx.x;
    if (i < cnt) dst[i] = f2bf(src[i]);
}

// ---------------- MLP: x[N,1] -> 16 -> 32 -> 64, ReLU each, bf16 out ----------------
__global__ void mlp_kernel(const float* __restrict__ x,
                           const float* __restrict__ w1, const float* __restrict__ b1,
                           const float* __restrict__ w2, const float* __restrict__ b2,
                           const float* __restrict__ w3, const float* __restrict__ b3,
                           unsigned short* __restrict__ h0, int n) {
    __shared__ float sw1[16], sb1[16], sw2[32 * 16], sb2[32], sw3[64 * 32], sb3[64];
    int tid = threadIdx.x;
    if (tid < 16) { sw1[tid] = w1[tid]; sb1[tid] = b1[tid]; }
    if (tid < 32) sb2[tid] = b2[tid];
    if (tid < 64) sb3[tid] = b3[tid];
    for (int i = tid; i < 512; i += 256) sw2[i] = w2[i];
    for (int i = tid; i < 2048; i += 256) sw3[i] = w3[i];
    __syncthreads();
    int node = blockIdx.x * 256 + tid;
    if (node >= n) return;
    float xv = x[node];
    float t1[16], t2[32];
#pragma unroll
    for (int i = 0; i < 16; i++) t1[i] = fmaxf(sw1[i] * xv + sb1[i], 0.f);
#pragma unroll
    for (int o = 0; o < 32; o++) {
        float a = sb2[o];
#pragma unroll
        for (int i = 0; i < 16; i++) a += sw2[o * 16 + i] * t1[i];
        t2[o] = fmaxf(a, 0.f);
    }
    unsigned short* hr = h0 + (size_t)node * 64;
    for (int o = 0; o < 64; o++) {
        float a = sb3[o];
#pragma unroll
        for (int i = 0; i < 32; i++) a += sw3[o * 32 + i] * t2[i];
        hr[o] = f2bf(fmaxf(a, 0.f));
    }
}

// ---------------- bf16 MFMA GEMM, 128xBN tile, BK=64, fused alpha epilogue ----------------
// C[r][o] = sum_k A[r][k]*W[o][k], A/W/C bf16, acc fp32.
// as_[r] += sum_o C[r][o]*avs[o] (fp32 atomics), same for ad_.
// K % 64 == 0, O % BN == 0 (grid.y = O/BN).
template <int BN>
__global__ __launch_bounds__(256) void gemm_mfma(
    const unsigned short* __restrict__ A, const unsigned short* __restrict__ Wb,
    unsigned short* __restrict__ Cb,
    const float* __restrict__ avs, const float* __restrict__ avd,
    float* __restrict__ as_, float* __restrict__ ad_, int n, int K, int O) {
    constexpr int SN = BN / 32;  // 16-col subtiles per wave (2 for BN=64, 1 for BN=32)
    __shared__ unsigned short As[128][72];  // 64 k + 8 pad: frag reads <=2-way banks (free)
    __shared__ unsigned short Ws[BN][72];
    int tid = threadIdx.x;
    int row0 = blockIdx.x * 128, col0 = blockIdx.y * BN;
    int w = tid >> 6, lane = tid & 63;
    int wr = w >> 1, wc = w & 1;
    int quad = lane >> 4, l15 = lane & 15;
    f32x4 acc[4][SN];
#pragma unroll
    for (int mi = 0; mi < 4; mi++)
#pragma unroll
        for (int ni = 0; ni < SN; ni++) acc[mi][ni] = (f32x4){0.f, 0.f, 0.f, 0.f};

    for (int k0 = 0; k0 < K; k0 += 64) {
        // stage A tile 128x64 bf16 (1024 uint4, 4 per thread)
#pragma unroll
        for (int i = tid; i < 1024; i += 256) {
            int r = i >> 3, c8 = i & 7;
            int gr = row0 + r;
            uint4 v = make_uint4(0u, 0u, 0u, 0u);
            if (gr < n) v = *(const uint4*)(A + (size_t)gr * K + k0 + c8 * 8);
            *(uint4*)&As[r][c8 * 8] = v;
        }
        // stage W tile BNx64 bf16
#pragma unroll
        for (int i = tid; i < BN * 8; i += 256) {
            int r = i >> 3, c8 = i & 7;
            uint4 v = *(const uint4*)(Wb + (size_t)(col0 + r) * K + k0 + c8 * 8);
            *(uint4*)&Ws[r][c8 * 8] = v;
        }
        __syncthreads();
#pragma unroll
        for (int kk = 0; kk < 64; kk += 32) {
            bf16x8 bfr[SN];
#pragma unroll
            for (int ni = 0; ni < SN; ni++)
                bfr[ni] = *(const bf16x8*)&Ws[wc * (BN / 2) + ni * 16 + l15][kk + quad * 8];
#pragma unroll
            for (int mi = 0; mi < 4; mi++) {
                bf16x8 afr = *(const bf16x8*)&As[wr * 64 + mi * 16 + l15][kk + quad * 8];
#pragma unroll
                for (int ni = 0; ni < SN; ni++)
                    acc[mi][ni] = __builtin_amdgcn_mfma_f32_16x16x32_bf16(afr, bfr[ni],
                                                                          acc[mi][ni], 0, 0, 0);
            }
        }
        __syncthreads();
    }
    // epilogue: C store (bf16) + fused alpha partial dots (fp32, pre-rounding)
    float avsv[SN], avdv[SN];
    int gc[SN];
#pragma unroll
    for (int ni = 0; ni < SN; ni++) {
        gc[ni] = col0 + wc * (BN / 2) + ni * 16 + l15;
        avsv[ni] = avs[gc[ni]];
        avdv[ni] = avd[gc[ni]];
    }
#pragma unroll
    for (int mi = 0; mi < 4; mi++) {
        int gm0 = row0 + wr * 64 + mi * 16 + quad * 4;
        float ps[4] = {0.f, 0.f, 0.f, 0.f}, pd[4] = {0.f, 0.f, 0.f, 0.f};
#pragma unroll
        for (int ni = 0; ni < SN; ni++) {
#pragma unroll
            for (int r = 0; r < 4; r++) {
                float d = acc[mi][ni][r];
                int gm = gm0 + r;
                if (gm < n) Cb[(size_t)gm * O + gc[ni]] = f2bf(d);
                ps[r] += d * avsv[ni];
                pd[r] += d * avdv[ni];
            }
        }
#pragma unroll
        for (int r = 0; r < 4; r++) {
#pragma unroll
            for (int m = 1; m <= 8; m <<= 1) {
                ps[r] += __shfl_xor(ps[r], m);
                pd[r] += __shfl_xor(pd[r], m);
            }
        }
        if (l15 == 0) {
#pragma unroll
            for (int r = 0; r < 4; r++) {
                int gm = gm0 + r;
                if (gm < n) {
                    atomicAdd(&as_[gm], ps[r]);
                    atomicAdd(&ad_[gm], pd[r]);
                }
            }
        }
    }
}

// ---------------- CSR build (by dst), self-loops appended at e >= E ----------------
__global__ void hist_kernel(const int* __restrict__ dst, int* __restrict__ deg, int E, int n) {
    int e = blockIdx.x * 256 + threadIdx.x;
    if (e >= E + n) return;
    int d = (e < E) ? dst[e] : (e - E);
    atomicAdd(&deg[d], 1);
}

__global__ void scan_block_sums(const int* __restrict__ deg, int* __restrict__ bsums, int n) {
    __shared__ int sdata[256];
    int tid = threadIdx.x;
    int base = blockIdx.x * 1024 + tid * 4;
    int s = 0;
    for (int i = 0; i < 4; i++) {
        int g = base + i;
        if (g < n) s += deg[g];
    }
    sdata[tid] = s;
    __syncthreads();
    for (int off = 128; off > 0; off >>= 1) {
        if (tid < off) sdata[tid] += sdata[tid + off];
        __syncthreads();
    }
    if (tid == 0) bsums[blockIdx.x] = sdata[0];
}

__global__ void scan_bsums(int* bsums, int nb, int* rowptr, int n) {
    if (threadIdx.x == 0 && blockIdx.x == 0) {
        int acc = 0;
        for (int i = 0; i < nb; i++) {
            int t = bsums[i];
            bsums[i] = acc;
            acc += t;
        }
        rowptr[n] = acc;
    }
}

__global__ void scan_write(const int* __restrict__ deg, const int* __restrict__ bsums,
                           int* __restrict__ rowptr, int* __restrict__ cursor, int n) {
    __shared__ int sdata[256];
    int tid = threadIdx.x;
    int base = blockIdx.x * 1024 + tid * 4;
    int v[4];
    int s = 0;
    for (int i = 0; i < 4; i++) {
        int g = base + i;
        v[i] = (g < n) ? deg[g] : 0;
        s += v[i];
    }
    sdata[tid] = s;
    __syncthreads();
    for (int off = 1; off < 256; off <<= 1) {
        int t = (tid >= off) ? sdata[tid - off] : 0;
        __syncthreads();
        sdata[tid] += t;
        __syncthreads();
    }
    int excl = sdata[tid] - s + bsums[blockIdx.x];
    for (int i = 0; i < 4; i++) {
        int g = base + i;
        if (g < n) { rowptr[g] = excl; cursor[g] = excl; }
        excl += v[i];
    }
}

__global__ void scatter_kernel(const int* __restrict__ esrc_in, const int* __restrict__ edst_in,
                               int* __restrict__ cursor, int* __restrict__ esrc, int E, int n) {
    int e = blockIdx.x * 256 + threadIdx.x;
    if (e >= E + n) return;
    int s, d;
    if (e < E) { s = esrc_in[e]; d = edst_in[e]; }
    else { s = e - E; d = e - E; }
    int pos = atomicAdd(&cursor[d], 1);
    esrc[pos] = s;
}

// ---------------- GAT aggregation: one wave per dst node, bf16 features ----------------
template <int O>
__global__ void gat_aggregate(const unsigned short* __restrict__ hl,
                              const float* __restrict__ as_, const float* __restrict__ ad_,
                              const int* __restrict__ rowptr, const int* __restrict__ esrc,
                              const float* __restrict__ bias, unsigned short* __restrict__ hout,
                              int n) {
    constexpr int C8 = O / 8;     // 16B chunks (8 bf16) per feature row
    constexpr int EPW = 64 / C8;  // edges per wave iteration
    int v = blockIdx.x * 4 + (threadIdx.x >> 6);
    int lane = threadIdx.x & 63;
    if (v >= n) return;
    int beg = rowptr[v], end = rowptr[v + 1];
    float adv = ad_[v];
    // pass 1: segment max (deg >= 1 via self-loop)
    float mymax = -1e30f;
    for (int j = beg + lane; j < end; j += 64) {
        float e = as_[esrc[j]] + adv;
        e = (e > 0.f) ? e : 0.2f * e;
        mymax = fmaxf(mymax, e);
    }
#pragma unroll
    for (int o = 32; o > 0; o >>= 1) mymax = fmaxf(mymax, __shfl_xor(mymax, o));
    // pass 2: denominator
    float mysum = 0.f;
    for (int j = beg + lane; j < end; j += 64) {
        float e = as_[esrc[j]] + adv;
        e = (e > 0.f) ? e : 0.2f * e;
        mysum += __expf(e - mymax);
    }
#pragma unroll
    for (int o = 32; o > 0; o >>= 1) mysum += __shfl_xor(mysum, o);
    float invden = 1.f / mysum;
    // pass 3: weighted aggregation, EPW edges concurrent, 16B bf16 gather per lane
    int sub = lane / C8;
    int c = lane % C8;
    float acc[8] = {0.f, 0.f, 0.f, 0.f, 0.f, 0.f, 0.f, 0.f};
    for (int j0 = beg; j0 < end; j0 += EPW) {
        int j = j0 + sub;
        bool valid = j < end;
        int s = valid ? esrc[j] : v;
        float e = as_[s] + adv;
        e = (e > 0.f) ? e : 0.2f * e;
        float alpha = valid ? __expf(e - mymax) * invden : 0.f;
        uint4 raw = ((const uint4*)(hl + (size_t)s * O))[c];
        acc[0] += alpha * __uint_as_float(raw.x << 16);
        acc[1] += alpha * __uint_as_float(raw.x & 0xffff0000u);
        acc[2] += alpha * __uint_as_float(raw.y << 16);
        acc[3] += alpha * __uint_as_float(raw.y & 0xffff0000u);
        acc[4] += alpha * __uint_as_float(raw.z << 16);
        acc[5] += alpha * __uint_as_float(raw.z & 0xffff0000u);
        acc[6] += alpha * __uint_as_float(raw.w << 16);
        acc[7] += alpha * __uint_as_float(raw.w & 0xffff0000u);
    }
#pragma unroll
    for (int o = C8; o < 64; o <<= 1)
#pragma unroll
        for (int k = 0; k < 8; k++) acc[k] += __shfl_xor(acc[k], o);
    if (sub == 0) {
        unsigned short ov[8];
#pragma unroll
        for (int k = 0; k < 8; k++) ov[k] = f2bf(fmaxf(acc[k] + bias[c * 8 + k], 0.f));
        uint4 packed;
        packed.x = (unsigned)ov[0] | ((unsigned)ov[1] << 16);
        packed.y = (unsigned)ov[2] | ((unsigned)ov[3] << 16);
        packed.z = (unsigned)ov[4] | ((unsigned)ov[5] << 16);
        packed.w = (unsigned)ov[6] | ((unsigned)ov[7] << 16);
        ((uint4*)(hout + (size_t)v * O))[c] = packed;
    }
}

// ---------------- pooling + readout ----------------
__global__ void pool_kernel(const unsigned short* __restrict__ h, const int* __restrict__ batch,
                            float* __restrict__ sums, float* __restrict__ cnt, int n) {
    int gt = blockIdx.x * blockDim.x + threadIdx.x;
    int node = gt >> 5, f = gt & 31;
    if (node >= n) return;
    int g = batch[node];
    atomicAdd(&sums[g * 32 + f], bf2f(h[(size_t)node * 32 + f]));
    if (f == 0) atomicAdd(&cnt[g], 1.f);
}

__global__ void final_kernel(const float* __restrict__ sums, const float* __restrict__ cnt,
                             const float* __restrict__ lw, const float* __restrict__ lb,
                             float* __restrict__ out, int G) {
    int g = blockIdx.x * blockDim.x + threadIdx.x;
    if (g >= G) return;
    float inv = 1.f / fmaxf(cnt[g], 1.f);
    float a = lb[0];
    for (int f = 0; f < 32; f++) a += sums[g * 32 + f] * inv * lw[f];
    out[g] = 1.f / (1.f + __expf(-a));
}

extern "C" void kernel_launch(void* const* d_in, const int* in_sizes, int n_in,
                              void* d_out, int out_size, void* d_ws, size_t ws_size,
                              hipStream_t stream) {
    const float* x = (const float*)d_in[0];
    const int* ei = (const int*)d_in[1];
    const int* batch = (const int*)d_in[2];
    const float* w1 = (const float*)d_in[3];
    const float* b1 = (const float*)d_in[4];
    const float* w2 = (const float*)d_in[5];
    const float* b2 = (const float*)d_in[6];
    const float* w3 = (const float*)d_in[7];
    const float* b3 = (const float*)d_in[8];
    const float* gw[5];
    const float* gas[5];
    const float* gad[5];
    const float* gb[5];
    for (int l = 0; l < 5; l++) {
        gw[l] = (const float*)d_in[9 + l * 4 + 0];
        gas[l] = (const float*)d_in[9 + l * 4 + 1];
        gad[l] = (const float*)d_in[9 + l * 4 + 2];
        gb[l] = (const float*)d_in[9 + l * 4 + 3];
    }
    const float* lw = (const float*)d_in[29];
    const float* lb = (const float*)d_in[30];
    float* out = (float*)d_out;

    int N = in_sizes[0];
    int E = in_sizes[1] / 2;
    int G = out_size;
    int Etot = E + N;

    char* ws = (char*)d_ws;
    size_t off = 0;
    auto alloc = [&](size_t bytes) -> void* {
        void* p = ws + off;
        off = (off + bytes + 255) & ~(size_t)255;
        return p;
    };
    unsigned short* actA = (unsigned short*)alloc((size_t)N * 256 * 2);  // ping (bf16)
    unsigned short* actB = (unsigned short*)alloc((size_t)N * 256 * 2);  // pong (bf16)
    float* asb = (float*)alloc((size_t)N * 4);
    float* adb = (float*)alloc((size_t)N * 4);
    int* deg = (int*)alloc((size_t)N * 4);
    int* rowptr = (int*)alloc((size_t)(N + 1) * 4);
    int* cursor = (int*)alloc((size_t)(N + 1) * 4);
    int* esrc = (int*)alloc((size_t)Etot * 4);
    int* bsums = (int*)alloc(4096);
    float* sums = (float*)alloc((size_t)G * 32 * 4);
    float* cnt = (float*)alloc((size_t)G * 4);
    const int wsz[5] = {128 * 64, 256 * 128, 128 * 256, 64 * 128, 32 * 64};
    unsigned short* wb[5];
    for (int l = 0; l < 5; l++) wb[l] = (unsigned short*)alloc((size_t)wsz[l] * 2);
    (void)ws_size;
    (void)n_in;

    // 0. convert GAT weights to bf16
    for (int l = 0; l < 5; l++)
        f2bf_kernel<<<(wsz[l] + 255) / 256, 256, 0, stream>>>(gw[l], wb[l], wsz[l]);

    // 1. node MLP -> actA [N,64] bf16
    mlp_kernel<<<(N + 255) / 256, 256, 0, stream>>>(x, w1, b1, w2, b2, w3, b3, actA, N);

    // 2. CSR by dst (edges + self-loops)
    hipMemsetAsync(deg, 0, (size_t)N * 4, stream);
    hist_kernel<<<(Etot + 255) / 256, 256, 0, stream>>>(ei + E, deg, E, N);
    int nb = (N + 1023) / 1024;
    scan_block_sums<<<nb, 256, 0, stream>>>(deg, bsums, N);
    scan_bsums<<<1, 64, 0, stream>>>(bsums, nb, rowptr, N);
    scan_write<<<nb, 256, 0, stream>>>(deg, bsums, rowptr, cursor, N);
    scatter_kernel<<<(Etot + 255) / 256, 256, 0, stream>>>(ei, ei + E, cursor, esrc, E, N);

    // 3. five GAT layers (MFMA GEMM w/ fused alpha, then softmax-aggregate)
    const int Ks[5] = {64, 128, 256, 128, 64};
    const int Os[5] = {128, 256, 128, 64, 32};
    int aggBlocks = (N + 3) / 4;
    int gx = (N + 127) / 128;
    for (int l = 0; l < 5; l++) {
        int K = Ks[l], O = Os[l];
        hipMemsetAsync(asb, 0, (size_t)N * 4, stream);
        hipMemsetAsync(adb, 0, (size_t)N * 4, stream);
        if (O >= 64) {
            dim3 grid(gx, O / 64);
            gemm_mfma<64><<<grid, 256, 0, stream>>>(actA, wb[l], actB, gas[l], gad[l], asb, adb,
                                                    N, K, O);
        } else {
            dim3 grid(gx, 1);
            gemm_mfma<32><<<grid, 256, 0, stream>>>(actA, wb[l], actB, gas[l], gad[l], asb, adb,
                                                    N, K, O);
        }
        switch (O) {
            case 256:
                gat_aggregate<256><<<aggBlocks, 256, 0, stream>>>(actB, asb, adb, rowptr, esrc,
                                                                  gb[l], actA, N);
                break;
            case 128:
                gat_aggregate<128><<<aggBlocks, 256, 0, stream>>>(actB, asb, adb, rowptr, esrc,
                                                                  gb[l], actA, N);
                break;
            case 64:
                gat_aggregate<64><<<aggBlocks, 256, 0, stream>>>(actB, asb, adb, rowptr, esrc,
                                                                 gb[l], actA, N);
                break;
            default:
                gat_aggregate<32><<<aggBlocks, 256, 0, stream>>>(actB, asb, adb, rowptr, esrc,
                                                                 gb[l], actA, N);
                break;
        }
    }

    // 4. mean pool + linear + sigmoid
    hipMemsetAsync(sums, 0, (size_t)G * 32 * 4, stream);
    hipMemsetAsync(cnt, 0, (size_t)G * 4, stream);
    pool_kernel<<<(N * 32 + 255) / 256, 256, 0, stream>>>(actA, batch, sums, cnt, N);
    final_kernel<<<(G + 255) / 256, 256, 0, stream>>>(sums, cnt, lw, lb, out, G);
}

// Round 5
// 679.934 us; speedup vs baseline: 2.4469x; 1.1773x over previous
//
#include <hip/hip_runtime.h>
#include <math.h>

typedef __attribute__((ext_vector_type(8))) __bf16 bf16x8;
typedef __attribute__((ext_vector_type(4))) float f32x4;

__device__ inline unsigned short f2bf(float f) {  // RNE
    unsigned int i = __float_as_uint(f);
    unsigned int r = i + 0x7fffu + ((i >> 16) & 1u);
    return (unsigned short)(r >> 16);
}
__device__ inline float bf2f(unsigned short u) {
    return __uint_as_float(((unsigned int)u) << 16);
}

// ---------------- fp32 -> bf16 conversion of all 5 GAT weight matrices ----------------
__global__ void f2bf5_kernel(const float* __restrict__ s0, const float* __restrict__ s1,
                             const float* __restrict__ s2, const float* __restrict__ s3,
                             const float* __restrict__ s4, unsigned short* __restrict__ dst) {
    int i = blockIdx.x * 256 + threadIdx.x;
    // segment offsets: 0, 8192, 40960, 73728, 81920, end 83968
    float v;
    if (i < 8192) v = s0[i];
    else if (i < 40960) v = s1[i - 8192];
    else if (i < 73728) v = s2[i - 40960];
    else if (i < 81920) v = s3[i - 73728];
    else if (i < 83968) v = s4[i - 81920];
    else return;
    dst[i] = f2bf(v);
}

// ---------------- MLP: x[N,1] -> 16 -> 32 -> 64, ReLU each, bf16 out (uint4 stores) ------
__global__ void mlp_kernel(const float* __restrict__ x,
                           const float* __restrict__ w1, const float* __restrict__ b1,
                           const float* __restrict__ w2, const float* __restrict__ b2,
                           const float* __restrict__ w3, const float* __restrict__ b3,
                           unsigned short* __restrict__ h0, int n) {
    __shared__ float sw1[16], sb1[16], sw2[32 * 16], sb2[32], sw3[64 * 32], sb3[64];
    int tid = threadIdx.x;
    if (tid < 16) { sw1[tid] = w1[tid]; sb1[tid] = b1[tid]; }
    if (tid < 32) sb2[tid] = b2[tid];
    if (tid < 64) sb3[tid] = b3[tid];
    for (int i = tid; i < 512; i += 256) sw2[i] = w2[i];
    for (int i = tid; i < 2048; i += 256) sw3[i] = w3[i];
    __syncthreads();
    int node = blockIdx.x * 256 + tid;
    if (node >= n) return;
    float xv = x[node];
    float t1[16], t2[32];
#pragma unroll
    for (int i = 0; i < 16; i++) t1[i] = fmaxf(sw1[i] * xv + sb1[i], 0.f);
#pragma unroll
    for (int o = 0; o < 32; o++) {
        float a = sb2[o];
#pragma unroll
        for (int i = 0; i < 16; i++) a += sw2[o * 16 + i] * t1[i];
        t2[o] = fmaxf(a, 0.f);
    }
    uint4* gp = (uint4*)(h0 + (size_t)node * 64);
#pragma unroll
    for (int c = 0; c < 8; c++) {
        unsigned int wvec[4];
#pragma unroll
        for (int p = 0; p < 4; p++) {
            int o = c * 8 + p * 2;
            float a0 = sb3[o], a1 = sb3[o + 1];
#pragma unroll
            for (int i = 0; i < 32; i++) {
                a0 += sw3[o * 32 + i] * t2[i];
                a1 += sw3[(o + 1) * 32 + i] * t2[i];
            }
            wvec[p] = (unsigned)f2bf(fmaxf(a0, 0.f)) | ((unsigned)f2bf(fmaxf(a1, 0.f)) << 16);
        }
        gp[c] = make_uint4(wvec[0], wvec[1], wvec[2], wvec[3]);
    }
}

// ---------------- bf16 MFMA GEMM, 128xBN tile, BK=64, fused alpha epilogue ----------------
template <int BN>
__global__ __launch_bounds__(256) void gemm_mfma(
    const unsigned short* __restrict__ A, const unsigned short* __restrict__ Wb,
    unsigned short* __restrict__ Cb,
    const float* __restrict__ avs, const float* __restrict__ avd,
    float* __restrict__ as_, float* __restrict__ ad_, int n, int K, int O) {
    constexpr int SN = BN / 32;
    __shared__ unsigned short As[128][72];  // +8 pad: frag reads <=2-way banks (free)
    __shared__ unsigned short Ws[BN][72];
    int tid = threadIdx.x;
    int row0 = blockIdx.x * 128, col0 = blockIdx.y * BN;
    int w = tid >> 6, lane = tid & 63;
    int wr = w >> 1, wc = w & 1;
    int quad = lane >> 4, l15 = lane & 15;
    f32x4 acc[4][SN];
#pragma unroll
    for (int mi = 0; mi < 4; mi++)
#pragma unroll
        for (int ni = 0; ni < SN; ni++) acc[mi][ni] = (f32x4){0.f, 0.f, 0.f, 0.f};

    for (int k0 = 0; k0 < K; k0 += 64) {
#pragma unroll
        for (int i = tid; i < 1024; i += 256) {
            int r = i >> 3, c8 = i & 7;
            int gr = row0 + r;
            uint4 v = make_uint4(0u, 0u, 0u, 0u);
            if (gr < n) v = *(const uint4*)(A + (size_t)gr * K + k0 + c8 * 8);
            *(uint4*)&As[r][c8 * 8] = v;
        }
#pragma unroll
        for (int i = tid; i < BN * 8; i += 256) {
            int r = i >> 3, c8 = i & 7;
            uint4 v = *(const uint4*)(Wb + (size_t)(col0 + r) * K + k0 + c8 * 8);
            *(uint4*)&Ws[r][c8 * 8] = v;
        }
        __syncthreads();
#pragma unroll
        for (int kk = 0; kk < 64; kk += 32) {
            bf16x8 bfr[SN];
#pragma unroll
            for (int ni = 0; ni < SN; ni++)
                bfr[ni] = *(const bf16x8*)&Ws[wc * (BN / 2) + ni * 16 + l15][kk + quad * 8];
#pragma unroll
            for (int mi = 0; mi < 4; mi++) {
                bf16x8 afr = *(const bf16x8*)&As[wr * 64 + mi * 16 + l15][kk + quad * 8];
#pragma unroll
                for (int ni = 0; ni < SN; ni++)
                    acc[mi][ni] = __builtin_amdgcn_mfma_f32_16x16x32_bf16(afr, bfr[ni],
                                                                          acc[mi][ni], 0, 0, 0);
            }
        }
        __syncthreads();
    }
    float avsv[SN], avdv[SN];
    int gc[SN];
#pragma unroll
    for (int ni = 0; ni < SN; ni++) {
        gc[ni] = col0 + wc * (BN / 2) + ni * 16 + l15;
        avsv[ni] = avs[gc[ni]];
        avdv[ni] = avd[gc[ni]];
    }
#pragma unroll
    for (int mi = 0; mi < 4; mi++) {
        int gm0 = row0 + wr * 64 + mi * 16 + quad * 4;
        float ps[4] = {0.f, 0.f, 0.f, 0.f}, pd[4] = {0.f, 0.f, 0.f, 0.f};
#pragma unroll
        for (int ni = 0; ni < SN; ni++) {
#pragma unroll
            for (int r = 0; r < 4; r++) {
                float d = acc[mi][ni][r];
                int gm = gm0 + r;
                if (gm < n) Cb[(size_t)gm * O + gc[ni]] = f2bf(d);
                ps[r] += d * avsv[ni];
                pd[r] += d * avdv[ni];
            }
        }
#pragma unroll
        for (int r = 0; r < 4; r++) {
#pragma unroll
            for (int m = 1; m <= 8; m <<= 1) {
                ps[r] += __shfl_xor(ps[r], m);
                pd[r] += __shfl_xor(pd[r], m);
            }
        }
        if (l15 == 0) {
#pragma unroll
            for (int r = 0; r < 4; r++) {
                int gm = gm0 + r;
                if (gm < n) {
                    atomicAdd(&as_[gm], ps[r]);
                    atomicAdd(&ad_[gm], pd[r]);
                }
            }
        }
    }
}

// ---------------- CSR build (by dst), self-loops appended at e >= E ----------------
__global__ void hist_kernel(const int* __restrict__ dst, int* __restrict__ deg, int E, int n) {
    int e = blockIdx.x * 256 + threadIdx.x;
    if (e >= E + n) return;
    int d = (e < E) ? dst[e] : (e - E);
    atomicAdd(&deg[d], 1);
}

__global__ void scan_block_sums(const int* __restrict__ deg, int* __restrict__ bsums, int n) {
    __shared__ int sdata[256];
    int tid = threadIdx.x;
    int base = blockIdx.x * 1024 + tid * 4;
    int s = 0;
    for (int i = 0; i < 4; i++) {
        int g = base + i;
        if (g < n) s += deg[g];
    }
    sdata[tid] = s;
    __syncthreads();
    for (int off = 128; off > 0; off >>= 1) {
        if (tid < off) sdata[tid] += sdata[tid + off];
        __syncthreads();
    }
    if (tid == 0) bsums[blockIdx.x] = sdata[0];
}

__global__ void scan_bsums(int* bsums, int nb, int* rowptr, int n) {
    if (threadIdx.x == 0 && blockIdx.x == 0) {
        int acc = 0;
        for (int i = 0; i < nb; i++) {
            int t = bsums[i];
            bsums[i] = acc;
            acc += t;
        }
        rowptr[n] = acc;
    }
}

__global__ void scan_write(const int* __restrict__ deg, const int* __restrict__ bsums,
                           int* __restrict__ rowptr, int* __restrict__ cursor, int n) {
    __shared__ int sdata[256];
    int tid = threadIdx.x;
    int base = blockIdx.x * 1024 + tid * 4;
    int v[4];
    int s = 0;
    for (int i = 0; i < 4; i++) {
        int g = base + i;
        v[i] = (g < n) ? deg[g] : 0;
        s += v[i];
    }
    sdata[tid] = s;
    __syncthreads();
    for (int off = 1; off < 256; off <<= 1) {
        int t = (tid >= off) ? sdata[tid - off] : 0;
        __syncthreads();
        sdata[tid] += t;
        __syncthreads();
    }
    int excl = sdata[tid] - s + bsums[blockIdx.x];
    for (int i = 0; i < 4; i++) {
        int g = base + i;
        if (g < n) { rowptr[g] = excl; cursor[g] = excl; }
        excl += v[i];
    }
}

__global__ void scatter_kernel(const int* __restrict__ esrc_in, const int* __restrict__ edst_in,
                               int* __restrict__ cursor, int* __restrict__ esrc, int E, int n) {
    int e = blockIdx.x * 256 + threadIdx.x;
    if (e >= E + n) return;
    int s, d;
    if (e < E) { s = esrc_in[e]; d = edst_in[e]; }
    else { s = e - E; d = e - E; }
    int pos = atomicAdd(&cursor[d], 1);
    esrc[pos] = s;
}

// ---------------- GAT aggregation: one wave per dst node, bf16 features ----------------
template <int O>
__global__ void gat_aggregate(const unsigned short* __restrict__ hl,
                              const float* __restrict__ as_, const float* __restrict__ ad_,
                              const int* __restrict__ rowptr, const int* __restrict__ esrc,
                              const float* __restrict__ bias, unsigned short* __restrict__ hout,
                              int n) {
    constexpr int C8 = O / 8;
    constexpr int EPW = 64 / C8;
    int v = blockIdx.x * 4 + (threadIdx.x >> 6);
    int lane = threadIdx.x & 63;
    if (v >= n) return;
    int beg = rowptr[v], end = rowptr[v + 1];
    float adv = ad_[v];
    float mymax = -1e30f;
    for (int j = beg + lane; j < end; j += 64) {
        float e = as_[esrc[j]] + adv;
        e = (e > 0.f) ? e : 0.2f * e;
        mymax = fmaxf(mymax, e);
    }
#pragma unroll
    for (int o = 32; o > 0; o >>= 1) mymax = fmaxf(mymax, __shfl_xor(mymax, o));
    float mysum = 0.f;
    for (int j = beg + lane; j < end; j += 64) {
        float e = as_[esrc[j]] + adv;
        e = (e > 0.f) ? e : 0.2f * e;
        mysum += __expf(e - mymax);
    }
#pragma unroll
    for (int o = 32; o > 0; o >>= 1) mysum += __shfl_xor(mysum, o);
    float invden = 1.f / mysum;
    int sub = lane / C8;
    int c = lane % C8;
    float acc[8] = {0.f, 0.f, 0.f, 0.f, 0.f, 0.f, 0.f, 0.f};
    for (int j0 = beg; j0 < end; j0 += EPW) {
        int j = j0 + sub;
        bool valid = j < end;
        int s = valid ? esrc[j] : v;
        float e = as_[s] + adv;
        e = (e > 0.f) ? e : 0.2f * e;
        float alpha = valid ? __expf(e - mymax) * invden : 0.f;
        uint4 raw = ((const uint4*)(hl + (size_t)s * O))[c];
        acc[0] += alpha * __uint_as_float(raw.x << 16);
        acc[1] += alpha * __uint_as_float(raw.x & 0xffff0000u);
        acc[2] += alpha * __uint_as_float(raw.y << 16);
        acc[3] += alpha * __uint_as_float(raw.y & 0xffff0000u);
        acc[4] += alpha * __uint_as_float(raw.z << 16);
        acc[5] += alpha * __uint_as_float(raw.z & 0xffff0000u);
        acc[6] += alpha * __uint_as_float(raw.w << 16);
        acc[7] += alpha * __uint_as_float(raw.w & 0xffff0000u);
    }
#pragma unroll
    for (int o = C8; o < 64; o <<= 1)
#pragma unroll
        for (int k = 0; k < 8; k++) acc[k] += __shfl_xor(acc[k], o);
    if (sub == 0) {
        unsigned short ov[8];
#pragma unroll
        for (int k = 0; k < 8; k++) ov[k] = f2bf(fmaxf(acc[k] + bias[c * 8 + k], 0.f));
        uint4 packed;
        packed.x = (unsigned)ov[0] | ((unsigned)ov[1] << 16);
        packed.y = (unsigned)ov[2] | ((unsigned)ov[3] << 16);
        packed.z = (unsigned)ov[4] | ((unsigned)ov[5] << 16);
        packed.w = (unsigned)ov[6] | ((unsigned)ov[7] << 16);
        ((uint4*)(hout + (size_t)v * O))[c] = packed;
    }
}

// ---------------- graph boundaries: start[g] = lower_bound(batch, g); start[G] = n -------
__global__ void graph_start_kernel(const int* __restrict__ batch, int* __restrict__ start,
                                   int n, int G) {
    int g = blockIdx.x * 256 + threadIdx.x;
    if (g > G) return;
    if (g == G) { start[G] = n; return; }
    int lo = 0, hi = n;
    while (lo < hi) {
        int mid = (lo + hi) >> 1;
        if (batch[mid] < g) lo = mid + 1;
        else hi = mid;
    }
    start[g] = lo;
}

// ---------------- fused mean-pool + linear + sigmoid: one block per graph ----------------
__global__ __launch_bounds__(256) void pool_final_kernel(
    const unsigned short* __restrict__ h, const int* __restrict__ start,
    const float* __restrict__ lw, const float* __restrict__ lb,
    float* __restrict__ out, int G) {
    __shared__ float red[8][33];
    int g = blockIdx.x;
    if (g >= G) return;
    int beg = start[g], end = start[g + 1];
    int tid = threadIdx.x;
    int nodeLane = tid >> 5, f = tid & 31;
    float acc = 0.f;
    for (int v = beg + nodeLane; v < end; v += 8)
        acc += bf2f(h[(size_t)v * 32 + f]);
    red[nodeLane][f] = acc;
    __syncthreads();
    if (tid < 32) {
        float s = 0.f;
#pragma unroll
        for (int i = 0; i < 8; i++) s += red[i][f];
        float inv = 1.f / fmaxf((float)(end - beg), 1.f);
        float val = s * inv * lw[f];
#pragma unroll
        for (int o = 16; o > 0; o >>= 1) val += __shfl_xor(val, o);
        if (f == 0) out[g] = 1.f / (1.f + __expf(-(val + lb[0])));  // lb: the R4 bug
    }
}

extern "C" void kernel_launch(void* const* d_in, const int* in_sizes, int n_in,
                              void* d_out, int out_size, void* d_ws, size_t ws_size,
                              hipStream_t stream) {
    const float* x = (const float*)d_in[0];
    const int* ei = (const int*)d_in[1];
    const int* batch = (const int*)d_in[2];
    const float* w1 = (const float*)d_in[3];
    const float* b1 = (const float*)d_in[4];
    const float* w2 = (const float*)d_in[5];
    const float* b2 = (const float*)d_in[6];
    const float* w3 = (const float*)d_in[7];
    const float* b3 = (const float*)d_in[8];
    const float* gw[5];
    const float* gas[5];
    const float* gad[5];
    const float* gb[5];
    for (int l = 0; l < 5; l++) {
        gw[l] = (const float*)d_in[9 + l * 4 + 0];
        gas[l] = (const float*)d_in[9 + l * 4 + 1];
        gad[l] = (const float*)d_in[9 + l * 4 + 2];
        gb[l] = (const float*)d_in[9 + l * 4 + 3];
    }
    const float* lw = (const float*)d_in[29];
    const float* lb = (const float*)d_in[30];
    float* out = (float*)d_out;

    int N = in_sizes[0];
    int E = in_sizes[1] / 2;
    int G = out_size;
    int Etot = E + N;

    char* ws = (char*)d_ws;
    size_t off = 0;
    auto alloc = [&](size_t bytes) -> void* {
        void* p = ws + off;
        off = (off + bytes + 255) & ~(size_t)255;
        return p;
    };
    unsigned short* actA = (unsigned short*)alloc((size_t)N * 256 * 2);
    unsigned short* actB = (unsigned short*)alloc((size_t)N * 256 * 2);
    float* asad = (float*)alloc((size_t)N * 8);  // as | ad contiguous -> one memset
    float* asb = asad;
    float* adb = asad + N;
    int* deg = (int*)alloc((size_t)N * 4);
    int* rowptr = (int*)alloc((size_t)(N + 1) * 4);
    int* cursor = (int*)alloc((size_t)(N + 1) * 4);
    int* esrc = (int*)alloc((size_t)Etot * 4);
    int* bsums = (int*)alloc(4096);
    int* gstart = (int*)alloc((size_t)(G + 1) * 4);
    unsigned short* wbAll = (unsigned short*)alloc((size_t)83968 * 2);
    const int woff[5] = {0, 8192, 40960, 73728, 81920};
    unsigned short* wb[5];
    for (int l = 0; l < 5; l++) wb[l] = wbAll + woff[l];
    (void)ws_size;
    (void)n_in;

    // 0. convert GAT weights to bf16 (single kernel)
    f2bf5_kernel<<<(83968 + 255) / 256, 256, 0, stream>>>(gw[0], gw[1], gw[2], gw[3], gw[4],
                                                          wbAll);

    // 1. node MLP -> actA [N,64] bf16
    mlp_kernel<<<(N + 255) / 256, 256, 0, stream>>>(x, w1, b1, w2, b2, w3, b3, actA, N);

    // 2. CSR by dst (edges + self-loops) + graph boundaries
    hipMemsetAsync(deg, 0, (size_t)N * 4, stream);
    hist_kernel<<<(Etot + 255) / 256, 256, 0, stream>>>(ei + E, deg, E, N);
    int nb = (N + 1023) / 1024;
    scan_block_sums<<<nb, 256, 0, stream>>>(deg, bsums, N);
    scan_bsums<<<1, 64, 0, stream>>>(bsums, nb, rowptr, N);
    scan_write<<<nb, 256, 0, stream>>>(deg, bsums, rowptr, cursor, N);
    scatter_kernel<<<(Etot + 255) / 256, 256, 0, stream>>>(ei, ei + E, cursor, esrc, E, N);
    graph_start_kernel<<<(G + 256) / 256, 256, 0, stream>>>(batch, gstart, N, G);

    // 3. five GAT layers (MFMA GEMM w/ fused alpha, then softmax-aggregate)
    const int Ks[5] = {64, 128, 256, 128, 64};
    const int Os[5] = {128, 256, 128, 64, 32};
    int aggBlocks = (N + 3) / 4;
    int gx = (N + 127) / 128;
    for (int l = 0; l < 5; l++) {
        int K = Ks[l], O = Os[l];
        hipMemsetAsync(asad, 0, (size_t)N * 8, stream);
        if (O >= 64) {
            dim3 grid(gx, O / 64);
            gemm_mfma<64><<<grid, 256, 0, stream>>>(actA, wb[l], actB, gas[l], gad[l], asb, adb,
                                                    N, K, O);
        } else {
            dim3 grid(gx, 1);
            gemm_mfma<32><<<grid, 256, 0, stream>>>(actA, wb[l], actB, gas[l], gad[l], asb, adb,
                                                    N, K, O);
        }
        switch (O) {
            case 256:
                gat_aggregate<256><<<aggBlocks, 256, 0, stream>>>(actB, asb, adb, rowptr, esrc,
                                                                  gb[l], actA, N);
                break;
            case 128:
                gat_aggregate<128><<<aggBlocks, 256, 0, stream>>>(actB, asb, adb, rowptr, esrc,
                                                                  gb[l], actA, N);
                break;
            case 64:
                gat_aggregate<64><<<aggBlocks, 256, 0, stream>>>(actB, asb, adb, rowptr, esrc,
                                                                 gb[l], actA, N);
                break;
            default:
                gat_aggregate<32><<<aggBlocks, 256, 0, stream>>>(actB, asb, adb, rowptr, esrc,
                                                                 gb[l], actA, N);
                break;
        }
    }

    // 4. fused mean pool + linear + sigmoid (no atomics)
    pool_final_kernel<<<G, 256, 0, stream>>>(actA, gstart, lw, lb, out, G);
}

// Round 6
// 573.861 us; speedup vs baseline: 2.8992x; 1.1848x over previous
//
#include <hip/hip_runtime.h>
#include <math.h>

typedef __attribute__((ext_vector_type(8))) __bf16 bf16x8;
typedef __attribute__((ext_vector_type(4))) float f32x4;

__device__ inline unsigned short f2bf(float f) {  // RNE
    unsigned int i = __float_as_uint(f);
    unsigned int r = i + 0x7fffu + ((i >> 16) & 1u);
    return (unsigned short)(r >> 16);
}
__device__ inline float bf2f(unsigned short u) {
    return __uint_as_float(((unsigned int)u) << 16);
}

// ---------------- prelude: MLP + weight-cast + graph starts + degree histogram -----------
// Block ranges: [0,mlpB) mlp | [mlpB,+f2bfB) weight cast | [+gsB) graph starts | rest hist.
__global__ __launch_bounds__(256) void prelude_kernel(
    const float* __restrict__ x,
    const float* __restrict__ w1, const float* __restrict__ b1,
    const float* __restrict__ w2, const float* __restrict__ b2,
    const float* __restrict__ w3, const float* __restrict__ b3,
    unsigned short* __restrict__ h0, int n,
    const float* __restrict__ g0, const float* __restrict__ g1, const float* __restrict__ g2,
    const float* __restrict__ g3, const float* __restrict__ g4,
    unsigned short* __restrict__ wbAll,
    const int* __restrict__ batch, int* __restrict__ gstart, int G,
    const int* __restrict__ dst, int* __restrict__ deg, int E,
    int mlpB, int f2bfB, int gsB) {
    int b = blockIdx.x;
    int tid = threadIdx.x;
    if (b < mlpB) {
        __shared__ float sw1[16], sb1[16], sw2[32 * 16], sb2[32], sw3[64 * 32], sb3[64];
        if (tid < 16) { sw1[tid] = w1[tid]; sb1[tid] = b1[tid]; }
        if (tid < 32) sb2[tid] = b2[tid];
        if (tid < 64) sb3[tid] = b3[tid];
        for (int i = tid; i < 512; i += 256) sw2[i] = w2[i];
        for (int i = tid; i < 2048; i += 256) sw3[i] = w3[i];
        __syncthreads();
        int node = b * 256 + tid;
        if (node >= n) return;
        float xv = x[node];
        float t1[16], t2[32];
#pragma unroll
        for (int i = 0; i < 16; i++) t1[i] = fmaxf(sw1[i] * xv + sb1[i], 0.f);
#pragma unroll
        for (int o = 0; o < 32; o++) {
            float a = sb2[o];
#pragma unroll
            for (int i = 0; i < 16; i++) a += sw2[o * 16 + i] * t1[i];
            t2[o] = fmaxf(a, 0.f);
        }
        uint4* gp = (uint4*)(h0 + (size_t)node * 64);
#pragma unroll
        for (int c = 0; c < 8; c++) {
            unsigned int wvec[4];
#pragma unroll
            for (int p = 0; p < 4; p++) {
                int o = c * 8 + p * 2;
                float a0 = sb3[o], a1 = sb3[o + 1];
#pragma unroll
                for (int i = 0; i < 32; i++) {
                    a0 += sw3[o * 32 + i] * t2[i];
                    a1 += sw3[(o + 1) * 32 + i] * t2[i];
                }
                wvec[p] =
                    (unsigned)f2bf(fmaxf(a0, 0.f)) | ((unsigned)f2bf(fmaxf(a1, 0.f)) << 16);
            }
            gp[c] = make_uint4(wvec[0], wvec[1], wvec[2], wvec[3]);
        }
    } else if (b < mlpB + f2bfB) {
        int i = (b - mlpB) * 256 + tid;
        // segment offsets: 0, 8192, 40960, 73728, 81920, end 83968
        float v;
        if (i < 8192) v = g0[i];
        else if (i < 40960) v = g1[i - 8192];
        else if (i < 73728) v = g2[i - 40960];
        else if (i < 81920) v = g3[i - 73728];
        else if (i < 83968) v = g4[i - 81920];
        else return;
        wbAll[i] = f2bf(v);
    } else if (b < mlpB + f2bfB + gsB) {
        int g = (b - mlpB - f2bfB) * 256 + tid;
        if (g > G) return;
        if (g == G) { gstart[G] = n; return; }
        int lo = 0, hi = n;
        while (lo < hi) {
            int mid = (lo + hi) >> 1;
            if (batch[mid] < g) lo = mid + 1;
            else hi = mid;
        }
        gstart[g] = lo;
    } else {
        int e = (b - mlpB - f2bfB - gsB) * 256 + tid;
        if (e >= E + n) return;
        int d = (e < E) ? dst[e] : (e - E);
        atomicAdd(&deg[d], 1);
    }
}

// ---------------- bf16 MFMA GEMM, 128xBN tile, BK=64, fused alpha epilogue ----------------
template <int BN>
__global__ __launch_bounds__(256) void gemm_mfma(
    const unsigned short* __restrict__ A, const unsigned short* __restrict__ Wb,
    unsigned short* __restrict__ Cb,
    const float* __restrict__ avs, const float* __restrict__ avd,
    float* __restrict__ as_, float* __restrict__ ad_, int n, int K, int O) {
    constexpr int SN = BN / 32;
    __shared__ unsigned short As[128][72];  // +8 pad: frag reads <=2-way banks (free)
    __shared__ unsigned short Ws[BN][72];
    int tid = threadIdx.x;
    int row0 = blockIdx.x * 128, col0 = blockIdx.y * BN;
    int w = tid >> 6, lane = tid & 63;
    int wr = w >> 1, wc = w & 1;
    int quad = lane >> 4, l15 = lane & 15;
    f32x4 acc[4][SN];
#pragma unroll
    for (int mi = 0; mi < 4; mi++)
#pragma unroll
        for (int ni = 0; ni < SN; ni++) acc[mi][ni] = (f32x4){0.f, 0.f, 0.f, 0.f};

    for (int k0 = 0; k0 < K; k0 += 64) {
#pragma unroll
        for (int i = tid; i < 1024; i += 256) {
            int r = i >> 3, c8 = i & 7;
            int gr = row0 + r;
            uint4 v = make_uint4(0u, 0u, 0u, 0u);
            if (gr < n) v = *(const uint4*)(A + (size_t)gr * K + k0 + c8 * 8);
            *(uint4*)&As[r][c8 * 8] = v;
        }
#pragma unroll
        for (int i = tid; i < BN * 8; i += 256) {
            int r = i >> 3, c8 = i & 7;
            uint4 v = *(const uint4*)(Wb + (size_t)(col0 + r) * K + k0 + c8 * 8);
            *(uint4*)&Ws[r][c8 * 8] = v;
        }
        __syncthreads();
#pragma unroll
        for (int kk = 0; kk < 64; kk += 32) {
            bf16x8 bfr[SN];
#pragma unroll
            for (int ni = 0; ni < SN; ni++)
                bfr[ni] = *(const bf16x8*)&Ws[wc * (BN / 2) + ni * 16 + l15][kk + quad * 8];
#pragma unroll
            for (int mi = 0; mi < 4; mi++) {
                bf16x8 afr = *(const bf16x8*)&As[wr * 64 + mi * 16 + l15][kk + quad * 8];
#pragma unroll
                for (int ni = 0; ni < SN; ni++)
                    acc[mi][ni] = __builtin_amdgcn_mfma_f32_16x16x32_bf16(afr, bfr[ni],
                                                                          acc[mi][ni], 0, 0, 0);
            }
        }
        __syncthreads();
    }
    float avsv[SN], avdv[SN];
    int gc[SN];
#pragma unroll
    for (int ni = 0; ni < SN; ni++) {
        gc[ni] = col0 + wc * (BN / 2) + ni * 16 + l15;
        avsv[ni] = avs[gc[ni]];
        avdv[ni] = avd[gc[ni]];
    }
#pragma unroll
    for (int mi = 0; mi < 4; mi++) {
        int gm0 = row0 + wr * 64 + mi * 16 + quad * 4;
        float ps[4] = {0.f, 0.f, 0.f, 0.f}, pd[4] = {0.f, 0.f, 0.f, 0.f};
#pragma unroll
        for (int ni = 0; ni < SN; ni++) {
#pragma unroll
            for (int r = 0; r < 4; r++) {
                float d = acc[mi][ni][r];
                int gm = gm0 + r;
                if (gm < n) Cb[(size_t)gm * O + gc[ni]] = f2bf(d);
                ps[r] += d * avsv[ni];
                pd[r] += d * avdv[ni];
            }
        }
#pragma unroll
        for (int r = 0; r < 4; r++) {
#pragma unroll
            for (int m = 1; m <= 8; m <<= 1) {
                ps[r] += __shfl_xor(ps[r], m);
                pd[r] += __shfl_xor(pd[r], m);
            }
        }
        if (l15 == 0) {
#pragma unroll
            for (int r = 0; r < 4; r++) {
                int gm = gm0 + r;
                if (gm < n) {
                    atomicAdd(&as_[gm], ps[r]);
                    atomicAdd(&ad_[gm], pd[r]);
                }
            }
        }
    }
}

// ---------------- scan: per-1024-chunk sums ----------------
__global__ void scan_block_sums(const int* __restrict__ deg, int* __restrict__ bsums, int n) {
    __shared__ int sdata[256];
    int tid = threadIdx.x;
    int base = blockIdx.x * 1024 + tid * 4;
    int s = 0;
    for (int i = 0; i < 4; i++) {
        int g = base + i;
        if (g < n) s += deg[g];
    }
    sdata[tid] = s;
    __syncthreads();
    for (int off = 128; off > 0; off >>= 1) {
        if (tid < off) sdata[tid] += sdata[tid + off];
        __syncthreads();
    }
    if (tid == 0) bsums[blockIdx.x] = sdata[0];
}

// ---------------- scan_write: inline bsums prefix (nb <= 256) + rowptr/cursor ----------------
__global__ void scan_write(const int* __restrict__ deg, const int* __restrict__ bsums,
                           int* __restrict__ rowptr, int* __restrict__ cursor, int n, int nb) {
    __shared__ int sdata[256];
    int tid = threadIdx.x;
    // base = sum(bsums[0..blockIdx.x))
    sdata[tid] = (tid < blockIdx.x && tid < nb) ? bsums[tid] : 0;
    __syncthreads();
    for (int off = 128; off > 0; off >>= 1) {
        if (tid < off) sdata[tid] += sdata[tid + off];
        __syncthreads();
    }
    int base = sdata[0];
    __syncthreads();
    int gbase = blockIdx.x * 1024 + tid * 4;
    int v[4];
    int s = 0;
    for (int i = 0; i < 4; i++) {
        int g = gbase + i;
        v[i] = (g < n) ? deg[g] : 0;
        s += v[i];
    }
    sdata[tid] = s;
    __syncthreads();
    for (int off = 1; off < 256; off <<= 1) {  // inclusive Hillis-Steele
        int t = (tid >= off) ? sdata[tid - off] : 0;
        __syncthreads();
        sdata[tid] += t;
        __syncthreads();
    }
    int excl = sdata[tid] - s + base;
    for (int i = 0; i < 4; i++) {
        int g = gbase + i;
        if (g < n) { rowptr[g] = excl; cursor[g] = excl; }
        excl += v[i];
    }
    if (blockIdx.x == gridDim.x - 1 && tid == 255) rowptr[n] = base + sdata[255];
}

__global__ void scatter_kernel(const int* __restrict__ esrc_in, const int* __restrict__ edst_in,
                               int* __restrict__ cursor, int* __restrict__ esrc, int E, int n) {
    int e = blockIdx.x * 256 + threadIdx.x;
    if (e >= E + n) return;
    int s, d;
    if (e < E) { s = esrc_in[e]; d = edst_in[e]; }
    else { s = e - E; d = e - E; }
    int pos = atomicAdd(&cursor[d], 1);
    esrc[pos] = s;
}

// ---------------- GAT aggregation: one wave per dst node, bf16 features ----------------
// Fast path (deg<=64): one edge per lane; alpha/src fetched via shuffle in pass 3.
// Also zeroes zeroBuf (next layer's alpha accumulators) as a grid-stride chore.
template <int O>
__global__ __launch_bounds__(256) void gat_aggregate(
    const unsigned short* __restrict__ hl, const float* __restrict__ as_,
    const float* __restrict__ ad_, const int* __restrict__ rowptr,
    const int* __restrict__ esrc, const float* __restrict__ bias,
    unsigned short* __restrict__ hout, int n, float* __restrict__ zeroBuf, int zeroCnt) {
    int gtid = blockIdx.x * 256 + threadIdx.x;
    if (gtid < zeroCnt) zeroBuf[gtid] = 0.f;
    constexpr int C8 = O / 8;
    constexpr int EPW = 64 / C8;
    int v = blockIdx.x * 4 + (threadIdx.x >> 6);
    int lane = threadIdx.x & 63;
    if (v >= n) return;
    int beg = rowptr[v], end = rowptr[v + 1];
    int deg = end - beg;
    float adv = ad_[v];
    int sub = lane / C8;
    int c = lane % C8;
    float acc[8] = {0.f, 0.f, 0.f, 0.f, 0.f, 0.f, 0.f, 0.f};
    if (deg <= 64) {
        // one edge per lane: compute e once, keep alpha/src in registers
        int sreg = v;
        float e = -1e30f;
        if (lane < deg) {
            sreg = esrc[beg + lane];
            float t = as_[sreg] + adv;
            e = (t > 0.f) ? t : 0.2f * t;
        }
        float m = e;
#pragma unroll
        for (int o = 32; o > 0; o >>= 1) m = fmaxf(m, __shfl_xor(m, o));
        float ex = (lane < deg) ? __expf(e - m) : 0.f;
        float sum = ex;
#pragma unroll
        for (int o = 32; o > 0; o >>= 1) sum += __shfl_xor(sum, o);
        float alpha_r = ex / sum;
        for (int j0 = 0; j0 < deg; j0 += EPW) {
            int idx = j0 + sub;
            int cidx = (idx < deg) ? idx : 0;
            float alpha = __shfl(alpha_r, cidx);
            int s2 = __shfl(sreg, cidx);
            if (idx >= deg) alpha = 0.f;
            uint4 raw = ((const uint4*)(hl + (size_t)s2 * O))[c];
            acc[0] += alpha * __uint_as_float(raw.x << 16);
            acc[1] += alpha * __uint_as_float(raw.x & 0xffff0000u);
            acc[2] += alpha * __uint_as_float(raw.y << 16);
            acc[3] += alpha * __uint_as_float(raw.y & 0xffff0000u);
            acc[4] += alpha * __uint_as_float(raw.z << 16);
            acc[5] += alpha * __uint_as_float(raw.z & 0xffff0000u);
            acc[6] += alpha * __uint_as_float(raw.w << 16);
            acc[7] += alpha * __uint_as_float(raw.w & 0xffff0000u);
        }
    } else {
        // generic 3-pass path (deg > 64, astronomically rare for this graph)
        float mymax = -1e30f;
        for (int j = beg + lane; j < end; j += 64) {
            float e = as_[esrc[j]] + adv;
            e = (e > 0.f) ? e : 0.2f * e;
            mymax = fmaxf(mymax, e);
        }
#pragma unroll
        for (int o = 32; o > 0; o >>= 1) mymax = fmaxf(mymax, __shfl_xor(mymax, o));
        float mysum = 0.f;
        for (int j = beg + lane; j < end; j += 64) {
            float e = as_[esrc[j]] + adv;
            e = (e > 0.f) ? e : 0.2f * e;
            mysum += __expf(e - mymax);
        }
#pragma unroll
        for (int o = 32; o > 0; o >>= 1) mysum += __shfl_xor(mysum, o);
        float invden = 1.f / mysum;
        for (int j0 = beg; j0 < end; j0 += EPW) {
            int j = j0 + sub;
            bool valid = j < end;
            int s = valid ? esrc[j] : v;
            float e = as_[s] + adv;
            e = (e > 0.f) ? e : 0.2f * e;
            float alpha = valid ? __expf(e - mymax) * invden : 0.f;
            uint4 raw = ((const uint4*)(hl + (size_t)s * O))[c];
            acc[0] += alpha * __uint_as_float(raw.x << 16);
            acc[1] += alpha * __uint_as_float(raw.x & 0xffff0000u);
            acc[2] += alpha * __uint_as_float(raw.y << 16);
            acc[3] += alpha * __uint_as_float(raw.y & 0xffff0000u);
            acc[4] += alpha * __uint_as_float(raw.z << 16);
            acc[5] += alpha * __uint_as_float(raw.z & 0xffff0000u);
            acc[6] += alpha * __uint_as_float(raw.w << 16);
            acc[7] += alpha * __uint_as_float(raw.w & 0xffff0000u);
        }
    }
#pragma unroll
    for (int o = C8; o < 64; o <<= 1)
#pragma unroll
        for (int k = 0; k < 8; k++) acc[k] += __shfl_xor(acc[k], o);
    if (sub == 0) {
        unsigned short ov[8];
#pragma unroll
        for (int k = 0; k < 8; k++) ov[k] = f2bf(fmaxf(acc[k] + bias[c * 8 + k], 0.f));
        uint4 packed;
        packed.x = (unsigned)ov[0] | ((unsigned)ov[1] << 16);
        packed.y = (unsigned)ov[2] | ((unsigned)ov[3] << 16);
        packed.z = (unsigned)ov[4] | ((unsigned)ov[5] << 16);
        packed.w = (unsigned)ov[6] | ((unsigned)ov[7] << 16);
        ((uint4*)(hout + (size_t)v * O))[c] = packed;
    }
}

// ---------------- fused mean-pool + linear + sigmoid: one block per graph ----------------
__global__ __launch_bounds__(256) void pool_final_kernel(
    const unsigned short* __restrict__ h, const int* __restrict__ start,
    const float* __restrict__ lw, const float* __restrict__ lb,
    float* __restrict__ out, int G) {
    __shared__ float red[8][33];
    int g = blockIdx.x;
    if (g >= G) return;
    int beg = start[g], end = start[g + 1];
    int tid = threadIdx.x;
    int nodeLane = tid >> 5, f = tid & 31;
    float acc = 0.f;
    for (int v = beg + nodeLane; v < end; v += 8)
        acc += bf2f(h[(size_t)v * 32 + f]);
    red[nodeLane][f] = acc;
    __syncthreads();
    if (tid < 32) {
        float s = 0.f;
#pragma unroll
        for (int i = 0; i < 8; i++) s += red[i][f];
        float inv = 1.f / fmaxf((float)(end - beg), 1.f);
        float val = s * inv * lw[f];
#pragma unroll
        for (int o = 16; o > 0; o >>= 1) val += __shfl_xor(val, o);
        if (f == 0) out[g] = 1.f / (1.f + __expf(-(val + lb[0])));
    }
}

extern "C" void kernel_launch(void* const* d_in, const int* in_sizes, int n_in,
                              void* d_out, int out_size, void* d_ws, size_t ws_size,
                              hipStream_t stream) {
    const float* x = (const float*)d_in[0];
    const int* ei = (const int*)d_in[1];
    const int* batch = (const int*)d_in[2];
    const float* w1 = (const float*)d_in[3];
    const float* b1 = (const float*)d_in[4];
    const float* w2 = (const float*)d_in[5];
    const float* b2 = (const float*)d_in[6];
    const float* w3 = (const float*)d_in[7];
    const float* b3 = (const float*)d_in[8];
    const float* gw[5];
    const float* gas[5];
    const float* gad[5];
    const float* gb[5];
    for (int l = 0; l < 5; l++) {
        gw[l] = (const float*)d_in[9 + l * 4 + 0];
        gas[l] = (const float*)d_in[9 + l * 4 + 1];
        gad[l] = (const float*)d_in[9 + l * 4 + 2];
        gb[l] = (const float*)d_in[9 + l * 4 + 3];
    }
    const float* lw = (const float*)d_in[29];
    const float* lb = (const float*)d_in[30];
    float* out = (float*)d_out;

    int N = in_sizes[0];
    int E = in_sizes[1] / 2;
    int G = out_size;
    int Etot = E + N;

    char* ws = (char*)d_ws;
    size_t off = 0;
    auto alloc = [&](size_t bytes) -> void* {
        void* p = ws + off;
        off = (off + bytes + 255) & ~(size_t)255;
        return p;
    };
    unsigned short* actA = (unsigned short*)alloc((size_t)N * 256 * 2);
    unsigned short* actB = (unsigned short*)alloc((size_t)N * 256 * 2);
    // zero-block: asad0 (2N f32) | asad1 (2N f32) | deg (N i32) — one memset
    char* zblock = (char*)alloc((size_t)N * 20);
    float* asad0 = (float*)zblock;
    float* asad1 = asad0 + (size_t)N * 2;
    int* deg = (int*)(zblock + (size_t)N * 16);
    int* rowptr = (int*)alloc((size_t)(N + 1) * 4);
    int* cursor = (int*)alloc((size_t)(N + 1) * 4);
    int* esrc = (int*)alloc((size_t)Etot * 4);
    int* bsums = (int*)alloc(4096);
    int* gstart = (int*)alloc((size_t)(G + 1) * 4);
    unsigned short* wbAll = (unsigned short*)alloc((size_t)83968 * 2);
    const int woff[5] = {0, 8192, 40960, 73728, 81920};
    unsigned short* wb[5];
    for (int l = 0; l < 5; l++) wb[l] = wbAll + woff[l];
    (void)ws_size;
    (void)n_in;

    // 0. zero asad0|asad1|deg in one memset
    hipMemsetAsync(zblock, 0, (size_t)N * 20, stream);

    // 1. prelude: mlp + weight cast + graph starts + degree hist
    int mlpB = (N + 255) / 256;
    int f2bfB = (83968 + 255) / 256;
    int gsB = (G + 1 + 255) / 256;
    int histB = (Etot + 255) / 256;
    prelude_kernel<<<mlpB + f2bfB + gsB + histB, 256, 0, stream>>>(
        x, w1, b1, w2, b2, w3, b3, actA, N, gw[0], gw[1], gw[2], gw[3], gw[4], wbAll, batch,
        gstart, G, ei + E, deg, E, mlpB, f2bfB, gsB);

    // 2. CSR scan + scatter
    int nb = (N + 1023) / 1024;
    scan_block_sums<<<nb, 256, 0, stream>>>(deg, bsums, N);
    scan_write<<<nb, 256, 0, stream>>>(deg, bsums, rowptr, cursor, N, nb);
    scatter_kernel<<<(Etot + 255) / 256, 256, 0, stream>>>(ei, ei + E, cursor, esrc, E, N);

    // 3. five GAT layers; aggregate zeroes next layer's alpha buffer (ping-pong)
    const int Ks[5] = {64, 128, 256, 128, 64};
    const int Os[5] = {128, 256, 128, 64, 32};
    int aggBlocks = (N + 3) / 4;
    int gx = (N + 127) / 128;
    for (int l = 0; l < 5; l++) {
        int K = Ks[l], O = Os[l];
        float* asb = (l & 1) ? asad1 : asad0;
        float* zbuf = (l & 1) ? asad0 : asad1;
        if (O >= 64) {
            dim3 grid(gx, O / 64);
            gemm_mfma<64><<<grid, 256, 0, stream>>>(actA, wb[l], actB, gas[l], gad[l], asb,
                                                    asb + N, N, K, O);
        } else {
            dim3 grid(gx, 1);
            gemm_mfma<32><<<grid, 256, 0, stream>>>(actA, wb[l], actB, gas[l], gad[l], asb,
                                                    asb + N, N, K, O);
        }
        switch (O) {
            case 256:
                gat_aggregate<256><<<aggBlocks, 256, 0, stream>>>(
                    actB, asb, asb + N, rowptr, esrc, gb[l], actA, N, zbuf, 2 * N);
                break;
            case 128:
                gat_aggregate<128><<<aggBlocks, 256, 0, stream>>>(
                    actB, asb, asb + N, rowptr, esrc, gb[l], actA, N, zbuf, 2 * N);
                break;
            case 64:
                gat_aggregate<64><<<aggBlocks, 256, 0, stream>>>(
                    actB, asb, asb + N, rowptr, esrc, gb[l], actA, N, zbuf, 2 * N);
                break;
            default:
                gat_aggregate<32><<<aggBlocks, 256, 0, stream>>>(
                    actB, asb, asb + N, rowptr, esrc, gb[l], actA, N, zbuf, 2 * N);
                break;
        }
    }

    // 4. fused mean pool + linear + sigmoid
    pool_final_kernel<<<G, 256, 0, stream>>>(actA, gstart, lw, lb, out, G);
}